// Round 12
// baseline (262.625 us; speedup 1.0000x reference)
//
#include <hip/hip_runtime.h>

// 3-layer GraphSAGE, N=100000, F=H=128, E=1.6M.
// bf16 features, weights hi/lo split -> 2-term MFMA.
// Dual activation layout (R11):
//  - Zrm: row-major ROOT rows (128 bf16) -- gather source.
//  - fo arrays: MFMA-fragment-order halves -- GEMM source (all sage2
//    loads 1KB-coalesced). root1<-prep, agg1/agg2<-aggZ, root2<-sage2<0>.
// THIS VERSION fixes R11's regression: prep's cvt_x phase is re-mapped so
// the fo store is COALESCED (wave = 16 nodes x 4 chunk-groups; lane index
// == fo slot index -> one contiguous 1KB fragment per store instruction).
// R11 had lanes 0-15 = one node's 16 chunks -> 32-64 lines/store, +25us.
// Same values, pure address permutation. aggZ = R0 verified body (gather
// structural: ~59us / 3.3TB/s / FETCH at per-XCD dedupe floor, R6+R10).

#define NN 100000
#define NB 391          // ceil(100000/256) buckets of 256 dst nodes
#define SLAB 5120       // slab capacity per bucket (mean 4096, sigma 64)
#define NGB 1563        // ceil(N/64) 64-node fragment groups

typedef short bf16x8 __attribute__((ext_vector_type(8)));
typedef float f32x4 __attribute__((ext_vector_type(4)));

static __device__ __forceinline__ float uaf(unsigned u) { return __uint_as_float(u); }
static __device__ __forceinline__ unsigned short f2bf(float f) {
  unsigned u = __float_as_uint(f);
  u += 0x7fffu + ((u >> 16) & 1u);
  return (unsigned short)(u >> 16);
}

// fo address (elements) for node nd, 16B-chunk c (features c*8..c*8+7 of a half)
static __device__ __forceinline__ size_t fo_addr16(int nd, int c) {
  return (size_t)(nd >> 6) * 8192 + (size_t)(c >> 2) * 2048 +
         (size_t)((nd >> 4) & 3) * 512 + (size_t)(((c & 3) << 4) + (nd & 15)) * 8;
}

// ---------------- fused prep: scatter | cvt_x | cvt_w | zero rows ----------------
__global__ __launch_bounds__(256) void k_prep(
    const int* __restrict__ src, const int* __restrict__ dst, int E, int SB,
    int* __restrict__ cursor, unsigned* __restrict__ pairs,
    const float* __restrict__ x, unsigned short* __restrict__ Zrm,
    unsigned short* __restrict__ root1,
    const float* __restrict__ W1l, const float* __restrict__ W1r,
    const float* __restrict__ W2l, const float* __restrict__ W2r,
    unsigned short* __restrict__ wt1h, unsigned short* __restrict__ wt1l,
    unsigned short* __restrict__ wt2h, unsigned short* __restrict__ wt2l) {
  __shared__ int h[NB];
  __shared__ int rb[NB];
  const int b = blockIdx.x;
  const int tid = threadIdx.x;
  const int XB = NGB;  // 1563 cvt_x blocks (64 nodes each)

  if (b < SB) {
    // ---- edge scatter into bucket slabs ----
    for (int i = tid; i < NB; i += 256) h[i] = 0;
    __syncthreads();
    int s[8], d[8];
    const int base = b * 2048 + tid * 8;
    #pragma unroll
    for (int i = 0; i < 8; i++) {
      int g = base + i;
      bool ok = g < E;
      s[i] = ok ? src[g] : 0;
      d[i] = ok ? dst[g] : -1;
      if (ok) atomicAdd(&h[d[i] >> 8], 1);
    }
    __syncthreads();
    for (int i = tid; i < NB; i += 256) {
      rb[i] = h[i] ? atomicAdd(&cursor[i], h[i]) : 0;
      h[i] = 0;
    }
    __syncthreads();
    #pragma unroll
    for (int i = 0; i < 8; i++) {
      if (d[i] >= 0) {
        int bk = d[i] >> 8;
        int off = rb[bk] + atomicAdd(&h[bk], 1);
        if (off < SLAB)
          pairs[(size_t)bk * SLAB + off] =
              ((unsigned)(d[i] & 255) << 17) | (unsigned)s[i];
      }
    }
  } else if (b < SB + XB) {
    // ---- x fp32 -> bf16: wave = 16 nodes; lane = fo slot (coalesced fo) ----
    const int bb = b - SB;                 // gblk 0..1562
    const int w = tid >> 6;
    const int lane = tid & 63;
    const int nd = bb * 64 + w * 16 + (lane & 15);
    if (nd < NN) {
      const size_t fb = (size_t)bb * 8192 + (size_t)w * 512 + (size_t)lane * 8;
      #pragma unroll
      for (int ch = 0; ch < 4; ch++) {
        const int c = ch * 4 + (lane >> 4);
        const float4* xp = (const float4*)(x + (size_t)nd * 128 + c * 8);
        float4 a = xp[0], bx = xp[1];
        float v[8] = {a.x, a.y, a.z, a.w, bx.x, bx.y, bx.z, bx.w};
        unsigned hh[8];
        #pragma unroll
        for (int i = 0; i < 8; i++) hh[i] = f2bf(v[i]);
        uint4 p;
        p.x = hh[0] | (hh[1] << 16); p.y = hh[2] | (hh[3] << 16);
        p.z = hh[4] | (hh[5] << 16); p.w = hh[6] | (hh[7] << 16);
        *(uint4*)(Zrm + (size_t)nd * 128 + c * 8) = p;
        *(uint4*)(root1 + fb + (size_t)ch * 2048) = p;  // contiguous 1KB/wave
      }
    }
  } else if (b < SB + XB + 64) {
    // ---- weight transpose + hi/lo split, MFMA-fragment layout ----
    #pragma unroll
    for (int it = 0; it < 4; it++) {
      int t = (b - SB - XB) * 1024 + it * 256 + tid;  // t < 65536
      int layer = t >> 15;
      int rem = t & 32767;
      int k = rem >> 7;
      int nn = rem & 127;
      const float* Wl = layer ? W2l : W1l;
      const float* Wr = layer ? W2r : W1r;
      float v = (k < 128) ? Wl[k * 128 + nn] : Wr[(k - 128) * 128 + nn];
      unsigned short hv = f2bf(v);
      unsigned short lv = f2bf(v - uaf(((unsigned)hv) << 16));
      const int frag = (nn >> 4) * 8 + (k >> 7) * 4 + ((k >> 5) & 3);
      const int lane = ((k >> 3) & 3) * 16 + (nn & 15);
      const int addr = frag * 512 + lane * 8 + (k & 7);
      (layer ? wt2h : wt1h)[addr] = hv;
      (layer ? wt2l : wt1l)[addr] = lv;
    }
  } else {
    // ---- zero row N of Zrm (padding row for gather) ----
    unsigned* zr = (unsigned*)(Zrm + (size_t)NN * 128);
    if (tid < 64) zr[tid] = 0;
  }
}

// ---------------- per-bucket CSR build ----------------
__global__ __launch_bounds__(256) void k_build(const unsigned* __restrict__ pairs,
                                               const int* __restrict__ cursor,
                                               int* __restrict__ beg, int* __restrict__ deg,
                                               int* __restrict__ csr, int N) {
  __shared__ int cnt[256];
  __shared__ int sd[256];
  __shared__ int cur[256];
  const int b = blockIdx.x;
  const int tid = threadIdx.x;
  const size_t p0 = (size_t)b * SLAB;
  int count = cursor[b];
  if (count > SLAB) count = SLAB;
  cnt[tid] = 0;
  cur[tid] = 0;
  __syncthreads();
  for (int i = tid; i < count; i += 256) atomicAdd(&cnt[pairs[p0 + i] >> 17], 1);
  __syncthreads();
  int v = cnt[tid];
  sd[tid] = v;
  __syncthreads();
  #pragma unroll
  for (int off = 1; off < 256; off <<= 1) {
    int u = (tid >= off) ? sd[tid - off] : 0;
    __syncthreads();
    sd[tid] += u;
    __syncthreads();
  }
  const int node = b * 256 + tid;
  if (node < N) {
    beg[node] = (int)p0 + (sd[tid] - v);
    deg[node] = v;
  }
  __syncthreads();
  for (int i = tid; i < count; i += 256) {
    unsigned pv = pairs[p0 + i];
    int dl = pv >> 17;
    int pos = (sd[dl] - cnt[dl]) + atomicAdd(&cur[dl], 1);
    csr[p0 + pos] = pv & 0x1ffff;
  }
}

// accumulate 8 bf16 (packed in uint4) into float acc[8] -- bit-exact unpack order
#define ACC8(v)                                   \
  acc[0] += uaf((v).x << 16);                     \
  acc[1] += uaf((v).x & 0xffff0000u);             \
  acc[2] += uaf((v).y << 16);                     \
  acc[3] += uaf((v).y & 0xffff0000u);             \
  acc[4] += uaf((v).z << 16);                     \
  acc[5] += uaf((v).z & 0xffff0000u);             \
  acc[6] += uaf((v).w << 16);                     \
  acc[7] += uaf((v).w & 0xffff0000u);

// ---------------- mean aggregation (R0 verified body; rm in, fo out) ----------------
__global__ __launch_bounds__(256) void k_aggZ(const unsigned short* __restrict__ Zrm,
                                              unsigned short* __restrict__ aggfo,
                                              const int* __restrict__ begA,
                                              const int* __restrict__ degA,
                                              const int* __restrict__ csr, int n) {
  const int wid = (blockIdx.x * blockDim.x + threadIdx.x) >> 6;
  const int lane = threadIdx.x & 63;
  if (wid >= n) return;
  const int beg = begA[wid];
  const int d = degA[wid];
  const int g = lane >> 4, c = lane & 15;
  float acc[8] = {0.f, 0.f, 0.f, 0.f, 0.f, 0.f, 0.f, 0.f};

  for (int base = 0; base < d; base += 64) {
    int m = d - base;
    if (m > 64) m = 64;
    int idx = csr[beg + base + (lane < m ? lane : 0)];
    for (int k = 0; k < m; k += 32) {
      uint4 vA[4], vB[4];
      const bool hasB = (k + 16) < m;
      #pragma unroll
      for (int u = 0; u < 4; u++) {
        int kk = k + u * 4 + g;
        int j = __shfl(idx, kk & 63);
        j = (kk < m) ? j : NN;  // zero row
        vA[u] = *(const uint4*)(Zrm + (size_t)j * 128 + c * 8);
      }
      if (hasB) {
        #pragma unroll
        for (int u = 0; u < 4; u++) {
          int kk = k + 16 + u * 4 + g;
          int j = __shfl(idx, kk & 63);
          j = (kk < m) ? j : NN;
          vB[u] = *(const uint4*)(Zrm + (size_t)j * 128 + c * 8);
        }
      }
      #pragma unroll
      for (int u = 0; u < 4; u++) { ACC8(vA[u]); }
      if (hasB) {
        #pragma unroll
        for (int u = 0; u < 4; u++) { ACC8(vB[u]); }
      }
    }
  }
  #pragma unroll
  for (int j = 0; j < 8; j++) {
    acc[j] += __shfl_xor(acc[j], 16);
    acc[j] += __shfl_xor(acc[j], 32);
  }
  const float inv = d > 0 ? 1.0f / (float)d : 0.f;
  if (g == 0) {
    unsigned h[8];
    #pragma unroll
    for (int j = 0; j < 8; j++) h[j] = f2bf(acc[j] * inv);
    uint4 p;
    p.x = h[0] | (h[1] << 16); p.y = h[2] | (h[3] << 16);
    p.z = h[4] | (h[5] << 16); p.w = h[6] | (h[7] << 16);
    *(uint4*)(aggfo + fo_addr16(wid, c)) = p;
  }
}

// ---------------- streaming MFMA SAGE layer (all-coalesced, fo in/out) ----------------
// acc[s][cc] = mfma(W_frag, Z_frag, acc): lane holds feat f'=cc*16+r16*4+r,
// node = m0+s*16+ln. A-frags read 1KB-coalesced from fo arrays.
// MODE 0: relu -> Zrm root rows + root-fo copy. MODE 1: fused layer-3.
template <int MODE>
__global__ __launch_bounds__(256, 2) void k_sage2(
    const unsigned short* __restrict__ aggfo, const unsigned short* __restrict__ rootfo,
    const unsigned short* __restrict__ WTh, const unsigned short* __restrict__ WTl,
    const float* __restrict__ bias,
    unsigned short* __restrict__ Zrm_out, unsigned short* __restrict__ rootfo_out,
    const float* __restrict__ w3l, const float* __restrict__ w3r,
    float* __restrict__ s2, float* __restrict__ r2, int n) {
  const int tid = threadIdx.x;
  const int lane = tid & 63;
  const int w = tid >> 6;
  const int ln = lane & 15;
  const int r16 = lane >> 4;
  const int m0 = blockIdx.x * 256 + w * 64;
  const size_t fbase = (size_t)(m0 >> 6) * 8192;  // wave's 64-node group

  f32x4 acc[4][8];
  #pragma unroll
  for (int s = 0; s < 4; s++)
    #pragma unroll
    for (int cc = 0; cc < 8; cc++) {
      acc[s][cc][0] = 0.f; acc[s][cc][1] = 0.f;
      acc[s][cc][2] = 0.f; acc[s][cc][3] = 0.f;
    }
  float4 bv4[8];
  #pragma unroll
  for (int cc = 0; cc < 8; cc++) bv4[cc] = *(const float4*)(bias + cc * 16 + r16 * 4);

  #pragma unroll
  for (int kh = 0; kh < 2; kh++) {
    const unsigned short* zf = kh ? rootfo : aggfo;
    bf16x8 a[4][4];
    #pragma unroll
    for (int ks = 0; ks < 4; ks++)
      #pragma unroll
      for (int s = 0; s < 4; s++)
        a[s][ks] = *(const bf16x8*)(zf + fbase + (size_t)ks * 2048 + s * 512 + lane * 8);
    #pragma unroll
    for (int ks = 0; ks < 4; ks++) {
      #pragma unroll
      for (int cg = 0; cg < 4; cg++) {
        bf16x8 bh[2], bl[2];
        #pragma unroll
        for (int j = 0; j < 2; j++) {
          const size_t o = (size_t)(((cg * 2 + j) * 8 + kh * 4 + ks) * 512 + lane * 8);
          bh[j] = *(const bf16x8*)(WTh + o);
          bl[j] = *(const bf16x8*)(WTl + o);
        }
        #pragma unroll
        for (int j = 0; j < 2; j++) {
          #pragma unroll
          for (int s = 0; s < 4; s++) {
            acc[s][cg * 2 + j] =
                __builtin_amdgcn_mfma_f32_16x16x32_bf16(bh[j], a[s][ks], acc[s][cg * 2 + j], 0, 0, 0);
            acc[s][cg * 2 + j] =
                __builtin_amdgcn_mfma_f32_16x16x32_bf16(bl[j], a[s][ks], acc[s][cg * 2 + j], 0, 0, 0);
          }
        }
      }
    }
  }

  if (MODE == 0) {
    #pragma unroll
    for (int s = 0; s < 4; s++) {
      const int node = m0 + s * 16 + ln;
      if (node < n) {
        unsigned short* op = Zrm_out + (size_t)node * 128 + r16 * 4;
        #pragma unroll
        for (int cc = 0; cc < 8; cc++) {
          ushort4 hq;
          hq.x = f2bf(fmaxf(acc[s][cc][0] + bv4[cc].x, 0.f));
          hq.y = f2bf(fmaxf(acc[s][cc][1] + bv4[cc].y, 0.f));
          hq.z = f2bf(fmaxf(acc[s][cc][2] + bv4[cc].z, 0.f));
          hq.w = f2bf(fmaxf(acc[s][cc][3] + bv4[cc].w, 0.f));
          *(ushort4*)(op + cc * 16) = hq;
          // fragment-order copy: f' = cc*16 + r16*4 + r
          //   ks = cc>>1, lane-slot = ((cc&1)*2 + (r16>>1))*16 + ln, e0 = (r16&1)*4
          const size_t fo = fbase + (size_t)(cc >> 1) * 2048 + (size_t)s * 512 +
                            (size_t)((((cc & 1) * 2 + (r16 >> 1)) << 4) + ln) * 8 +
                            (r16 & 1) * 4;
          *(ushort4*)(rootfo_out + fo) = hq;
        }
      }
    }
  } else {
    float4 wl4[8], wr4[8];
    #pragma unroll
    for (int cc = 0; cc < 8; cc++) {
      wl4[cc] = *(const float4*)(w3l + cc * 16 + r16 * 4);
      wr4[cc] = *(const float4*)(w3r + cc * 16 + r16 * 4);
    }
    #pragma unroll
    for (int s = 0; s < 4; s++) {
      float sl = 0.f, sr = 0.f;
      #pragma unroll
      for (int cc = 0; cc < 8; cc++) {
        float v0 = fmaxf(acc[s][cc][0] + bv4[cc].x, 0.f);
        float v1 = fmaxf(acc[s][cc][1] + bv4[cc].y, 0.f);
        float v2 = fmaxf(acc[s][cc][2] + bv4[cc].z, 0.f);
        float v3 = fmaxf(acc[s][cc][3] + bv4[cc].w, 0.f);
        sl += v0 * wl4[cc].x + v1 * wl4[cc].y + v2 * wl4[cc].z + v3 * wl4[cc].w;
        sr += v0 * wr4[cc].x + v1 * wr4[cc].y + v2 * wr4[cc].z + v3 * wr4[cc].w;
      }
      sl += __shfl_xor(sl, 16); sl += __shfl_xor(sl, 32);
      sr += __shfl_xor(sr, 16); sr += __shfl_xor(sr, 32);
      const int node = m0 + s * 16 + ln;
      if (r16 == 0 && node < n) {
        s2[node] = sl;
        r2[node] = sr;
      }
    }
  }
}

// ---------------- final scalar aggregation (16 lanes/node) ----------------
__global__ __launch_bounds__(256) void k_out3(const float* __restrict__ s2,
                                              const float* __restrict__ r2,
                                              const int* __restrict__ beg,
                                              const int* __restrict__ deg,
                                              const int* __restrict__ csr,
                                              const float* __restrict__ b3,
                                              float* __restrict__ out, int n) {
  int t = blockIdx.x * blockDim.x + threadIdx.x;
  int node = t >> 4;
  int ln = t & 15;
  if (node >= n) return;
  int bg = beg[node], d = deg[node];
  float s = 0.f;
  for (int i = ln; i < d; i += 16) s += s2[csr[bg + i]];
  s += __shfl_xor(s, 1); s += __shfl_xor(s, 2);
  s += __shfl_xor(s, 4); s += __shfl_xor(s, 8);
  if (ln == 0) out[node] = s / (d > 0 ? (float)d : 1.0f) + r2[node] + b3[0];
}

extern "C" void kernel_launch(void* const* d_in, const int* in_sizes, int n_in,
                              void* d_out, int out_size, void* d_ws, size_t ws_size,
                              hipStream_t stream) {
  const float* x   = (const float*)d_in[0];
  const int*   ei  = (const int*)d_in[1];
  const float* W1l = (const float*)d_in[2];
  const float* W1r = (const float*)d_in[3];
  const float* b1  = (const float*)d_in[4];
  const float* W2l = (const float*)d_in[5];
  const float* W2r = (const float*)d_in[6];
  const float* b2  = (const float*)d_in[7];
  const float* W3l = (const float*)d_in[8];
  const float* W3r = (const float*)d_in[9];
  const float* b3  = (const float*)d_in[10];
  float* out = (float*)d_out;

  const int N = NN;
  const int E = in_sizes[1] / 2;
  const int* src = ei;
  const int* dst = ei + E;

  char* ws = (char*)d_ws;
  size_t off = 0;
  auto alloc = [&](size_t bytes) -> char* {
    char* p = ws + off;
    off = (off + bytes + 255) & ~(size_t)255;
    return p;
  };
  int* cursor = (int*)alloc((NB + 1) * 4);
  unsigned* pairs = (unsigned*)alloc((size_t)NB * SLAB * 4);
  int* csr  = (int*)alloc(((size_t)NB * SLAB + 128) * 4);
  int* beg  = (int*)alloc((size_t)N * 4);
  int* deg  = (int*)alloc((size_t)N * 4);
  float* s2 = (float*)alloc((size_t)N * 4);
  float* r2 = (float*)alloc((size_t)N * 4);
  unsigned short* wt1h = (unsigned short*)alloc(128 * 256 * 2);
  unsigned short* wt1l = (unsigned short*)alloc(128 * 256 * 2);
  unsigned short* wt2h = (unsigned short*)alloc(128 * 256 * 2);
  unsigned short* wt2l = (unsigned short*)alloc(128 * 256 * 2);
  unsigned short* Zrm   = (unsigned short*)alloc((size_t)(N + 1) * 128 * 2);  // shared rm root
  unsigned short* root1 = (unsigned short*)alloc((size_t)NGB * 8192 * 2);     // x root fo
  unsigned short* agg1  = (unsigned short*)alloc((size_t)NGB * 8192 * 2);     // L1 agg fo
  unsigned short* root2 = (unsigned short*)alloc((size_t)NGB * 8192 * 2);     // relu1 root fo
  unsigned short* agg2  = root1;  // alias: root1 dead after sage2-L1

  hipMemsetAsync(cursor, 0, (NB + 1) * 4, stream);
  // zero tail gblk (OOB node slots) of each fo array -> finite zeros in GEMM
  const size_t tail = (size_t)(NGB - 1) * 8192 * 2;
  hipMemsetAsync((char*)root1 + tail, 0, 8192 * 2, stream);
  hipMemsetAsync((char*)agg1 + tail, 0, 8192 * 2, stream);
  hipMemsetAsync((char*)root2 + tail, 0, 8192 * 2, stream);

  // ---- fused prep: edge scatter | x->bf16 (rm + fo) | weight split | zero row ----
  const int SB = (E + 2047) / 2048;         // 782 scatter blocks
  const int XB = NGB;                       // 1563 cvt_x blocks (64 nodes each)
  k_prep<<<SB + XB + 64 + 1, 256, 0, stream>>>(
      src, dst, E, SB, cursor, pairs, x, Zrm, root1,
      W1l, W1r, W2l, W2r, wt1h, wt1l, wt2h, wt2l);
  k_build<<<NB, 256, 0, stream>>>(pairs, cursor, beg, deg, csr, N);

  const int wb = (N * 64 + 255) / 256;
  const int sb = (N + 255) / 256;
  // ---- layer 1 ----
  k_aggZ<<<wb, 256, 0, stream>>>(Zrm, agg1, beg, deg, csr, N);
  k_sage2<0><<<sb, 256, 0, stream>>>(agg1, root1, wt1h, wt1l, b1, Zrm, root2,
                                     nullptr, nullptr, nullptr, nullptr, N);
  // ---- layer 2 (+ fused layer-3 transform) ----
  k_aggZ<<<wb, 256, 0, stream>>>(Zrm, agg2, beg, deg, csr, N);
  k_sage2<1><<<sb, 256, 0, stream>>>(agg2, root2, wt2h, wt2l, b2, nullptr, nullptr,
                                     W3l, W3r, s2, r2, N);
  // ---- layer 3 scalar aggregation ----
  k_out3<<<(N * 16 + 255) / 256, 256, 0, stream>>>(s2, r2, beg, deg, csr, b3, out, N);
}

// Round 13
// 248.853 us; speedup vs baseline: 1.0553x; 1.0553x over previous
//
#include <hip/hip_runtime.h>

// 3-layer GraphSAGE, N=100000, F=H=128, E=1.6M.
// bf16 features, weights hi/lo split -> 2-term MFMA.
// THIS VERSION: single row-major activation layout + LDS-staged GEMM tiles.
//  - Zrm [N+slack][128]: x, then relu1 (sage2<0> overwrites own rows) --
//    gather source AND GEMM root source.
//  - Zagg [N+slack][128]: mean-agg rows (aggZ out, R0 store pattern).
//  - k_sage2: each wave stages its CONTIGUOUS 64-row x 128-feat half-tile
//    (16KB) via 16 coalesced 1KB loads into a private XOR-swizzled LDS tile
//    (byte = nl*256 + ((2f)^((nl&7)<<4))), reads MFMA fragments as
//    ds_read_b128 (swizzle -> exactly 128B/cy, conflict-free), swapped-op
//    MFMA (R9), coalesced epilogue. No fo arrays, no dual writes.
// Kills R11/R12's +25.6MB prep write tax (prep time ~ write volume: 86MB
// ->60MB) while making ALL sage2 accesses coalesced. aggZ = R0 verified
// body (gather structural: ~59us / 3.3TB/s / per-XCD dedupe floor).

#define NN 100000
#define NB 391          // ceil(100000/256) buckets of 256 dst nodes
#define SLAB 5120       // slab capacity per bucket (mean 4096, sigma 64)

typedef short bf16x8 __attribute__((ext_vector_type(8)));
typedef float f32x4 __attribute__((ext_vector_type(4)));

static __device__ __forceinline__ float uaf(unsigned u) { return __uint_as_float(u); }
static __device__ __forceinline__ unsigned short f2bf(float f) {
  unsigned u = __float_as_uint(f);
  u += 0x7fffu + ((u >> 16) & 1u);
  return (unsigned short)(u >> 16);
}

// ---------------- fused prep: scatter | cvt_x | cvt_w | zero rows ----------------
__global__ __launch_bounds__(256) void k_prep(
    const int* __restrict__ src, const int* __restrict__ dst, int E, int SB,
    int* __restrict__ cursor, unsigned* __restrict__ pairs,
    const float* __restrict__ x, unsigned short* __restrict__ Zrm,
    const float* __restrict__ W1l, const float* __restrict__ W1r,
    const float* __restrict__ W2l, const float* __restrict__ W2r,
    unsigned short* __restrict__ wt1h, unsigned short* __restrict__ wt1l,
    unsigned short* __restrict__ wt2h, unsigned short* __restrict__ wt2l) {
  __shared__ int h[NB];
  __shared__ int rb[NB];
  const int b = blockIdx.x;
  const int tid = threadIdx.x;
  const int XB = NN * 16 / 256;  // 6250 cvt_x blocks

  if (b < SB) {
    // ---- edge scatter into bucket slabs ----
    for (int i = tid; i < NB; i += 256) h[i] = 0;
    __syncthreads();
    int s[8], d[8];
    const int base = b * 2048 + tid * 8;
    #pragma unroll
    for (int i = 0; i < 8; i++) {
      int g = base + i;
      bool ok = g < E;
      s[i] = ok ? src[g] : 0;
      d[i] = ok ? dst[g] : -1;
      if (ok) atomicAdd(&h[d[i] >> 8], 1);
    }
    __syncthreads();
    for (int i = tid; i < NB; i += 256) {
      rb[i] = h[i] ? atomicAdd(&cursor[i], h[i]) : 0;
      h[i] = 0;
    }
    __syncthreads();
    #pragma unroll
    for (int i = 0; i < 8; i++) {
      if (d[i] >= 0) {
        int bk = d[i] >> 8;
        int off = rb[bk] + atomicAdd(&h[bk], 1);
        if (off < SLAB)
          pairs[(size_t)bk * SLAB + off] =
              ((unsigned)(d[i] & 255) << 17) | (unsigned)s[i];
      }
    }
  } else if (b < SB + XB) {
    // ---- x fp32 -> bf16 row-major root rows ----
    int t = (b - SB) * 256 + tid;      // t < N*16
    int node = t >> 4, c = t & 15;
    const float4* xp = (const float4*)(x + (size_t)node * 128 + c * 8);
    float4 a = xp[0], bb = xp[1];
    float v[8] = {a.x, a.y, a.z, a.w, bb.x, bb.y, bb.z, bb.w};
    unsigned hh[8];
    #pragma unroll
    for (int i = 0; i < 8; i++) hh[i] = f2bf(v[i]);
    uint4 p;
    p.x = hh[0] | (hh[1] << 16); p.y = hh[2] | (hh[3] << 16);
    p.z = hh[4] | (hh[5] << 16); p.w = hh[6] | (hh[7] << 16);
    *(uint4*)(Zrm + (size_t)node * 128 + c * 8) = p;
  } else if (b < SB + XB + 64) {
    // ---- weight transpose + hi/lo split, MFMA-fragment layout ----
    //   frag = (nn>>4)*8 + (k>>7)*4 + ((k>>5)&3); lane = ((k>>3)&3)*16+(nn&15)
    #pragma unroll
    for (int it = 0; it < 4; it++) {
      int t = (b - SB - XB) * 1024 + it * 256 + tid;  // t < 65536
      int layer = t >> 15;
      int rem = t & 32767;
      int k = rem >> 7;
      int nn = rem & 127;
      const float* Wl = layer ? W2l : W1l;
      const float* Wr = layer ? W2r : W1r;
      float v = (k < 128) ? Wl[k * 128 + nn] : Wr[(k - 128) * 128 + nn];
      unsigned short hv = f2bf(v);
      unsigned short lv = f2bf(v - uaf(((unsigned)hv) << 16));
      const int frag = (nn >> 4) * 8 + (k >> 7) * 4 + ((k >> 5) & 3);
      const int lane = ((k >> 3) & 3) * 16 + (nn & 15);
      const int addr = frag * 512 + lane * 8 + (k & 7);
      (layer ? wt2h : wt1h)[addr] = hv;
      (layer ? wt2l : wt1l)[addr] = lv;
    }
  } else {
    // ---- zero row N of Zrm (padding row for gather; stays 0 both layers) ----
    unsigned* zr = (unsigned*)(Zrm + (size_t)NN * 128);
    if (tid < 64) zr[tid] = 0;
  }
}

// ---------------- per-bucket CSR build ----------------
__global__ __launch_bounds__(256) void k_build(const unsigned* __restrict__ pairs,
                                               const int* __restrict__ cursor,
                                               int* __restrict__ beg, int* __restrict__ deg,
                                               int* __restrict__ csr, int N) {
  __shared__ int cnt[256];
  __shared__ int sd[256];
  __shared__ int cur[256];
  const int b = blockIdx.x;
  const int tid = threadIdx.x;
  const size_t p0 = (size_t)b * SLAB;
  int count = cursor[b];
  if (count > SLAB) count = SLAB;
  cnt[tid] = 0;
  cur[tid] = 0;
  __syncthreads();
  for (int i = tid; i < count; i += 256) atomicAdd(&cnt[pairs[p0 + i] >> 17], 1);
  __syncthreads();
  int v = cnt[tid];
  sd[tid] = v;
  __syncthreads();
  #pragma unroll
  for (int off = 1; off < 256; off <<= 1) {
    int u = (tid >= off) ? sd[tid - off] : 0;
    __syncthreads();
    sd[tid] += u;
    __syncthreads();
  }
  const int node = b * 256 + tid;
  if (node < N) {
    beg[node] = (int)p0 + (sd[tid] - v);
    deg[node] = v;
  }
  __syncthreads();
  for (int i = tid; i < count; i += 256) {
    unsigned pv = pairs[p0 + i];
    int dl = pv >> 17;
    int pos = (sd[dl] - cnt[dl]) + atomicAdd(&cur[dl], 1);
    csr[p0 + pos] = pv & 0x1ffff;
  }
}

// accumulate 8 bf16 (packed in uint4) into float acc[8] -- bit-exact unpack order
#define ACC8(v)                                   \
  acc[0] += uaf((v).x << 16);                     \
  acc[1] += uaf((v).x & 0xffff0000u);             \
  acc[2] += uaf((v).y << 16);                     \
  acc[3] += uaf((v).y & 0xffff0000u);             \
  acc[4] += uaf((v).z << 16);                     \
  acc[5] += uaf((v).z & 0xffff0000u);             \
  acc[6] += uaf((v).w << 16);                     \
  acc[7] += uaf((v).w & 0xffff0000u);

// ---------------- mean aggregation (R0 verified body; rm in, rm out) ----------------
__global__ __launch_bounds__(256) void k_aggZ(const unsigned short* __restrict__ Zrm,
                                              unsigned short* __restrict__ Zagg,
                                              const int* __restrict__ begA,
                                              const int* __restrict__ degA,
                                              const int* __restrict__ csr, int n) {
  const int wid = (blockIdx.x * blockDim.x + threadIdx.x) >> 6;
  const int lane = threadIdx.x & 63;
  if (wid >= n) return;
  const int beg = begA[wid];
  const int d = degA[wid];
  const int g = lane >> 4, c = lane & 15;
  float acc[8] = {0.f, 0.f, 0.f, 0.f, 0.f, 0.f, 0.f, 0.f};

  for (int base = 0; base < d; base += 64) {
    int m = d - base;
    if (m > 64) m = 64;
    int idx = csr[beg + base + (lane < m ? lane : 0)];
    for (int k = 0; k < m; k += 32) {
      uint4 vA[4], vB[4];
      const bool hasB = (k + 16) < m;
      #pragma unroll
      for (int u = 0; u < 4; u++) {
        int kk = k + u * 4 + g;
        int j = __shfl(idx, kk & 63);
        j = (kk < m) ? j : NN;  // zero row
        vA[u] = *(const uint4*)(Zrm + (size_t)j * 128 + c * 8);
      }
      if (hasB) {
        #pragma unroll
        for (int u = 0; u < 4; u++) {
          int kk = k + 16 + u * 4 + g;
          int j = __shfl(idx, kk & 63);
          j = (kk < m) ? j : NN;
          vB[u] = *(const uint4*)(Zrm + (size_t)j * 128 + c * 8);
        }
      }
      #pragma unroll
      for (int u = 0; u < 4; u++) { ACC8(vA[u]); }
      if (hasB) {
        #pragma unroll
        for (int u = 0; u < 4; u++) { ACC8(vB[u]); }
      }
    }
  }
  #pragma unroll
  for (int j = 0; j < 8; j++) {
    acc[j] += __shfl_xor(acc[j], 16);
    acc[j] += __shfl_xor(acc[j], 32);
  }
  const float inv = d > 0 ? 1.0f / (float)d : 0.f;
  if (g == 0) {
    unsigned h[8];
    #pragma unroll
    for (int j = 0; j < 8; j++) h[j] = f2bf(acc[j] * inv);
    uint4 p;
    p.x = h[0] | (h[1] << 16); p.y = h[2] | (h[3] << 16);
    p.z = h[4] | (h[5] << 16); p.w = h[6] | (h[7] << 16);
    *(uint4*)(Zagg + (size_t)wid * 128 + c * 8) = p;
  }
}

// ---------------- MFMA SAGE layer: LDS-staged swizzled tiles ----------------
// Per wave: 64 contiguous rows. Per kh half: stage 16KB (16 coalesced 1KB
// loads) into private swizzled LDS tile, read 16 ds_read_b128 fragments.
// acc[s][cc] = mfma(W_frag, Z_frag, acc) (swapped operands, R9): lane holds
// feat f'=cc*16+r16*4+r of node m0+s*16+ln. Values bit-identical to R9/R12.
// MODE 0: relu -> Zout rows (aliases Zroot; each wave RMWs only its own rows).
// MODE 1: fused layer-3 transform -> s2/r2.
template <int MODE>
__global__ __launch_bounds__(256, 2) void k_sage2(
    const unsigned short* __restrict__ Zagg, const unsigned short* __restrict__ Zroot,
    const unsigned short* __restrict__ WTh, const unsigned short* __restrict__ WTl,
    const float* __restrict__ bias, unsigned short* __restrict__ Zout,
    const float* __restrict__ w3l, const float* __restrict__ w3r,
    float* __restrict__ s2, float* __restrict__ r2, int n) {
  __shared__ __align__(16) unsigned short tile[4][8192];  // 16 KB per wave
  const int tid = threadIdx.x;
  const int lane = tid & 63;
  const int w = tid >> 6;
  const int ln = lane & 15;
  const int r16 = lane >> 4;
  const int m0 = blockIdx.x * 256 + w * 64;
  char* T = (char*)tile[w];

  f32x4 acc[4][8];
  #pragma unroll
  for (int s = 0; s < 4; s++)
    #pragma unroll
    for (int cc = 0; cc < 8; cc++) {
      acc[s][cc][0] = 0.f; acc[s][cc][1] = 0.f;
      acc[s][cc][2] = 0.f; acc[s][cc][3] = 0.f;
    }
  float4 bv4[8];
  #pragma unroll
  for (int cc = 0; cc < 8; cc++) bv4[cc] = *(const float4*)(bias + cc * 16 + r16 * 4);

  #pragma unroll
  for (int kh = 0; kh < 2; kh++) {
    const unsigned short* zsrc = kh ? Zroot : Zagg;
    // ---- stage 64 rows x 128 feats, XOR-swizzled (coalesced 1KB/instr) ----
    #pragma unroll
    for (int i = 0; i < 16; i++) {
      const int nl = i * 4 + r16;
      uint4 v = *(const uint4*)(zsrc + (size_t)(m0 + nl) * 128 + ln * 8);
      *(uint4*)(T + nl * 256 + ((ln * 16) ^ ((nl & 7) << 4))) = v;
    }
    // ---- fragment reads: a[s][ks][e] = Z[m0+s*16+ln][ks*32+r16*8+e] ----
    bf16x8 a[4][4];
    #pragma unroll
    for (int ks = 0; ks < 4; ks++)
      #pragma unroll
      for (int s = 0; s < 4; s++) {
        const int nl = s * 16 + ln;
        a[s][ks] = *(const bf16x8*)(T + nl * 256 +
                                    ((ks * 64 + r16 * 16) ^ ((nl & 7) << 4)));
      }
    // ---- MFMAs (same order as R9/R12 -> bit-identical) ----
    #pragma unroll
    for (int ks = 0; ks < 4; ks++) {
      #pragma unroll
      for (int cg = 0; cg < 4; cg++) {
        bf16x8 bh[2], bl[2];
        #pragma unroll
        for (int j = 0; j < 2; j++) {
          const size_t o = (size_t)(((cg * 2 + j) * 8 + kh * 4 + ks) * 512 + lane * 8);
          bh[j] = *(const bf16x8*)(WTh + o);
          bl[j] = *(const bf16x8*)(WTl + o);
        }
        #pragma unroll
        for (int j = 0; j < 2; j++) {
          #pragma unroll
          for (int s = 0; s < 4; s++) {
            acc[s][cg * 2 + j] =
                __builtin_amdgcn_mfma_f32_16x16x32_bf16(bh[j], a[s][ks], acc[s][cg * 2 + j], 0, 0, 0);
            acc[s][cg * 2 + j] =
                __builtin_amdgcn_mfma_f32_16x16x32_bf16(bl[j], a[s][ks], acc[s][cg * 2 + j], 0, 0, 0);
          }
        }
      }
    }
  }

  if (MODE == 0) {
    #pragma unroll
    for (int s = 0; s < 4; s++) {
      const int node = m0 + s * 16 + ln;
      if (node < n) {
        unsigned short* op = Zout + (size_t)node * 128 + r16 * 4;
        #pragma unroll
        for (int cc = 0; cc < 8; cc++) {
          ushort4 hq;
          hq.x = f2bf(fmaxf(acc[s][cc][0] + bv4[cc].x, 0.f));
          hq.y = f2bf(fmaxf(acc[s][cc][1] + bv4[cc].y, 0.f));
          hq.z = f2bf(fmaxf(acc[s][cc][2] + bv4[cc].z, 0.f));
          hq.w = f2bf(fmaxf(acc[s][cc][3] + bv4[cc].w, 0.f));
          *(ushort4*)(op + cc * 16) = hq;
        }
      }
    }
  } else {
    float4 wl4[8], wr4[8];
    #pragma unroll
    for (int cc = 0; cc < 8; cc++) {
      wl4[cc] = *(const float4*)(w3l + cc * 16 + r16 * 4);
      wr4[cc] = *(const float4*)(w3r + cc * 16 + r16 * 4);
    }
    #pragma unroll
    for (int s = 0; s < 4; s++) {
      float sl = 0.f, sr = 0.f;
      #pragma unroll
      for (int cc = 0; cc < 8; cc++) {
        float v0 = fmaxf(acc[s][cc][0] + bv4[cc].x, 0.f);
        float v1 = fmaxf(acc[s][cc][1] + bv4[cc].y, 0.f);
        float v2 = fmaxf(acc[s][cc][2] + bv4[cc].z, 0.f);
        float v3 = fmaxf(acc[s][cc][3] + bv4[cc].w, 0.f);
        sl += v0 * wl4[cc].x + v1 * wl4[cc].y + v2 * wl4[cc].z + v3 * wl4[cc].w;
        sr += v0 * wr4[cc].x + v1 * wr4[cc].y + v2 * wr4[cc].z + v3 * wr4[cc].w;
      }
      sl += __shfl_xor(sl, 16); sl += __shfl_xor(sl, 32);
      sr += __shfl_xor(sr, 16); sr += __shfl_xor(sr, 32);
      const int node = m0 + s * 16 + ln;
      if (r16 == 0 && node < n) {
        s2[node] = sl;
        r2[node] = sr;
      }
    }
  }
}

// ---------------- final scalar aggregation (16 lanes/node) ----------------
__global__ __launch_bounds__(256) void k_out3(const float* __restrict__ s2,
                                              const float* __restrict__ r2,
                                              const int* __restrict__ beg,
                                              const int* __restrict__ deg,
                                              const int* __restrict__ csr,
                                              const float* __restrict__ b3,
                                              float* __restrict__ out, int n) {
  int t = blockIdx.x * blockDim.x + threadIdx.x;
  int node = t >> 4;
  int ln = t & 15;
  if (node >= n) return;
  int bg = beg[node], d = deg[node];
  float s = 0.f;
  for (int i = ln; i < d; i += 16) s += s2[csr[bg + i]];
  s += __shfl_xor(s, 1); s += __shfl_xor(s, 2);
  s += __shfl_xor(s, 4); s += __shfl_xor(s, 8);
  if (ln == 0) out[node] = s / (d > 0 ? (float)d : 1.0f) + r2[node] + b3[0];
}

extern "C" void kernel_launch(void* const* d_in, const int* in_sizes, int n_in,
                              void* d_out, int out_size, void* d_ws, size_t ws_size,
                              hipStream_t stream) {
  const float* x   = (const float*)d_in[0];
  const int*   ei  = (const int*)d_in[1];
  const float* W1l = (const float*)d_in[2];
  const float* W1r = (const float*)d_in[3];
  const float* b1  = (const float*)d_in[4];
  const float* W2l = (const float*)d_in[5];
  const float* W2r = (const float*)d_in[6];
  const float* b2  = (const float*)d_in[7];
  const float* W3l = (const float*)d_in[8];
  const float* W3r = (const float*)d_in[9];
  const float* b3  = (const float*)d_in[10];
  float* out = (float*)d_out;

  const int N = NN;
  const int E = in_sizes[1] / 2;
  const int* src = ei;
  const int* dst = ei + E;

  char* ws = (char*)d_ws;
  size_t off = 0;
  auto alloc = [&](size_t bytes) -> char* {
    char* p = ws + off;
    off = (off + bytes + 255) & ~(size_t)255;
    return p;
  };
  int* cursor = (int*)alloc((NB + 1) * 4);
  unsigned* pairs = (unsigned*)alloc((size_t)NB * SLAB * 4);
  int* csr  = (int*)alloc(((size_t)NB * SLAB + 128) * 4);
  int* beg  = (int*)alloc((size_t)N * 4);
  int* deg  = (int*)alloc((size_t)N * 4);
  float* s2 = (float*)alloc((size_t)N * 4);
  float* r2 = (float*)alloc((size_t)N * 4);
  unsigned short* wt1h = (unsigned short*)alloc(128 * 256 * 2);
  unsigned short* wt1l = (unsigned short*)alloc(128 * 256 * 2);
  unsigned short* wt2h = (unsigned short*)alloc(128 * 256 * 2);
  unsigned short* wt2l = (unsigned short*)alloc(128 * 256 * 2);
  // +160 slack rows: sage2 tail-block staging reads up to row 100095;
  // row NN is the zero pad for the gather (prep zeroes it, epilogue guards it).
  unsigned short* Zrm  = (unsigned short*)alloc((size_t)(N + 160) * 128 * 2);
  unsigned short* Zagg = (unsigned short*)alloc((size_t)(N + 160) * 128 * 2);

  hipMemsetAsync(cursor, 0, (NB + 1) * 4, stream);

  // ---- fused prep: edge scatter | x->bf16 | weight split | zero row ----
  const int SB = (E + 2047) / 2048;         // 782 scatter blocks
  const int XB = N * 16 / 256;              // 6250 cvt_x blocks
  k_prep<<<SB + XB + 64 + 1, 256, 0, stream>>>(
      src, dst, E, SB, cursor, pairs, x, Zrm,
      W1l, W1r, W2l, W2r, wt1h, wt1l, wt2h, wt2l);
  k_build<<<NB, 256, 0, stream>>>(pairs, cursor, beg, deg, csr, N);

  const int wb = (N * 64 + 255) / 256;
  const int sb = (N + 255) / 256;           // 391 GEMM blocks
  // ---- layer 1 ----
  k_aggZ<<<wb, 256, 0, stream>>>(Zrm, Zagg, beg, deg, csr, N);
  k_sage2<0><<<sb, 256, 0, stream>>>(Zagg, Zrm, wt1h, wt1l, b1, Zrm,
                                     nullptr, nullptr, nullptr, nullptr, N);
  // ---- layer 2 (+ fused layer-3 transform) ----
  k_aggZ<<<wb, 256, 0, stream>>>(Zrm, Zagg, beg, deg, csr, N);
  k_sage2<1><<<sb, 256, 0, stream>>>(Zagg, Zrm, wt2h, wt2l, b2, nullptr,
                                     W3l, W3r, s2, r2, N);
  // ---- layer 3 scalar aggregation ----
  k_out3<<<(N * 16 + 255) / 256, 256, 0, stream>>>(s2, r2, beg, deg, csr, b3, out, N);
}